// Round 12
// baseline (720.255 us; speedup 1.0000x reference)
//
#include <hip/hip_runtime.h>
#include <hip/hip_bf16.h>

#define BT 2
#define TT 1024
#define CC 2048
#define HH 32
#define MM (BT*TT)
#define TCH 512          // scan/prep chunk length
#define NCH (TT/TCH)     // 2 chunks
// record layout (896 B): [0,512) per-kl 16B {ew0,ew1,r(bf16x2),kf(bf16x2)}
//                        [512,768) per-kl 8B {kk(bf16x2), -kk*a(bf16x2)}
//                        [768,896) v[64] bf16
#define RECB 896

typedef __attribute__((ext_vector_type(8))) short short8;
typedef __attribute__((ext_vector_type(4))) float floatx4;

static __device__ __forceinline__ float bf2f(__hip_bfloat16 x){ return __bfloat162float(x); }
static __device__ __forceinline__ __hip_bfloat16 f2bf(float x){ return __float2bfloat16(x); }
static __device__ __forceinline__ float sigm(float x){ return 1.0f/(1.0f + expf(-x)); }
static __device__ __forceinline__ float u2f(unsigned short u){
  union { unsigned int i; float f; } x; x.i = ((unsigned int)u) << 16; return x.f;
}
static __device__ __forceinline__ float ulo(unsigned int u){ return __uint_as_float(u << 16); }
static __device__ __forceinline__ float uhi(unsigned int u){ return __uint_as_float(u & 0xffff0000u); }
static __device__ __forceinline__ unsigned short bfbits(float x){
  __hip_bfloat16 h = f2bf(x);
  unsigned short s; __builtin_memcpy(&s, &h, 2); return s;
}
static __device__ __forceinline__ unsigned int pkbf(float lo, float hi){
  return (unsigned int)bfbits(lo) | ((unsigned int)bfbits(hi) << 16);
}

// ---- async global->LDS staging (direct DMA, no VGPR round trip) ----------------
#if defined(__has_builtin)
#if __has_builtin(__builtin_amdgcn_global_load_lds)
#define HAVE_GLL 1
#endif
#endif

#ifdef HAVE_GLL
static __device__ __forceinline__ void gll16(const void* g, void* l){
  __builtin_amdgcn_global_load_lds(
      (__attribute__((address_space(1))) void*)const_cast<void*>(g),
      (__attribute__((address_space(3))) void*)l,
      16, 0, 0);
}
#endif

// ---- VALU-only cross-lane reductions (DPP + permlane_swap builtins) ------------
#define DPP_ADD(x, ctrl) ((x) + __int_as_float(__builtin_amdgcn_update_dpp(0, __float_as_int(x), (ctrl), 0xF, 0xF, true)))

#if defined(__has_builtin)
#if __has_builtin(__builtin_amdgcn_permlane16_swap) && __has_builtin(__builtin_amdgcn_permlane32_swap)
#define HAVE_PLSWAP 1
#endif
#endif

#ifdef HAVE_PLSWAP
typedef unsigned int uint2v __attribute__((ext_vector_type(2)));
static __device__ __forceinline__ float row16_pair_add(float x){   // x[i] + x[i^16]
  unsigned int u = __float_as_uint(x);
  uint2v r = __builtin_amdgcn_permlane16_swap(u, u, false, false);
  return __uint_as_float(r[0]) + __uint_as_float(r[1]);
}
static __device__ __forceinline__ float half32_pair_add(float x){  // x[i] + x[i^32]
  unsigned int u = __float_as_uint(x);
  uint2v r = __builtin_amdgcn_permlane32_swap(u, u, false, false);
  return __uint_as_float(r[0]) + __uint_as_float(r[1]);
}
#else
static __device__ __forceinline__ float row16_pair_add(float x){ return x + __shfl_xor(x, 16); }
static __device__ __forceinline__ float half32_pair_add(float x){ return x + __shfl_xor(x, 32); }
#endif

static __device__ __forceinline__ float red8(float x){   // sum over lanes sharing tid>>3
  x = DPP_ADD(x, 0xB1);    // quad_perm xor1
  x = DPP_ADD(x, 0x4E);    // quad_perm xor2
  x = DPP_ADD(x, 0x141);   // row_half_mirror
  return x;
}
static __device__ __forceinline__ float red64(float x){  // sum over whole wave
  x = DPP_ADD(x, 0xB1);
  x = DPP_ADD(x, 0x4E);
  x = DPP_ADD(x, 0x124);   // row_ror:4
  x = DPP_ADD(x, 0x128);   // row_ror:8
  x = row16_pair_add(x);
  return half32_pair_add(x);
}

// ---------------- K0: transpose + convert weights: Wt[n][k] = bf16(W[k][n]) ------
__global__ __launch_bounds__(256) void tcvt_kernel(
    const float* __restrict__ W, __hip_bfloat16* __restrict__ Wt,
    int K, int N, int Npad)
{
  __shared__ float tile[32][33];
  const int bn = blockIdx.x*32, bk = blockIdx.y*32;
  const int tx = threadIdx.x & 31, ty0 = threadIdx.x >> 5;   // 8 rows/pass
#pragma unroll
  for (int i=0;i<4;++i){
    const int kk = bk + ty0 + i*8;
    float val = 0.f;
    if (kk < K && bn + tx < N) val = W[(size_t)kk*N + bn + tx];
    tile[ty0 + i*8][tx] = val;
  }
  __syncthreads();
#pragma unroll
  for (int i=0;i<4;++i){
    const int nn = bn + ty0 + i*8;
    const int kk = bk + tx;
    if (nn < Npad && kk < K) Wt[(size_t)nn*K + kk] = f2bf(tile[tx][ty0 + i*8]);
  }
}

// ---------------- K1: rmsnorm(x_in, ln1) -> x_bf bf16; x[:, -1] -> seg1 f32 ------
__global__ __launch_bounds__(256) void rmsnorm1_kernel(
    const float* __restrict__ x_in,
    const float* __restrict__ ln1,
    __hip_bfloat16* __restrict__ x_bf,
    float* __restrict__ x_last)
{
  const int m = blockIdx.x;
  const int tid = threadIdx.x;
  const int c = tid * 8;
  const float* xp = x_in + (size_t)m*CC + c;
  float v[8]; float ss = 0.f;
#pragma unroll
  for (int i=0;i<8;++i){ v[i] = xp[i]; ss += v[i]*v[i]; }
  ss = red64(ss);
  __shared__ float wsum[4];
  if ((tid&63)==0) wsum[tid>>6] = ss;
  __syncthreads();
  ss = wsum[0]+wsum[1]+wsum[2]+wsum[3];
  const float sc = rsqrtf(ss * (1.0f/CC) + 1e-6f);
#pragma unroll
  for (int i=0;i<8;++i) {
    const float y = ln1[c+i] * v[i] * sc;
    x_bf[(size_t)m*CC + c + i] = f2bf(y);
    if ((m % TT) == TT-1) x_last[(size_t)(m/TT)*CC + c + i] = y;
  }
}

// ------- MFMA bf16 GEMM: C[M,N] = A_bf16[M,K](lda) @ Wt_bf16[Npad,K]^T -----------
// Staging via global_load_lds width=16 (m97 structure). ACT==1: fused act576.
template<bool F32OUT, int ACT>
__global__ __launch_bounds__(256) void mgemm(
    const __hip_bfloat16* __restrict__ A, int lda,
    const __hip_bfloat16* __restrict__ Bt,
    void* __restrict__ C, int N, int K)
{
  __shared__ __align__(16) short As[128*32];
  __shared__ __align__(16) short Bs[128*32];
  const int tid = threadIdx.x;
  const int bm = blockIdx.x * 128;
  const int bn = blockIdx.y * 128;
  const int wid = tid >> 6;
  const int lane = tid & 63;
  const int m16 = lane & 15, quad = lane >> 4;
  const int wm = wid & 1, wn = wid >> 1;
  const int lrow = tid >> 2;          // 0..63
  const int lcol = (tid & 3) * 8;     // bf16 elems: 0,8,16,24

  floatx4 acc[4][4];
#pragma unroll
  for (int i=0;i<4;++i)
#pragma unroll
    for (int j=0;j<4;++j) acc[i][j] = (floatx4){0.f,0.f,0.f,0.f};

  char* asl = (char*)As + tid*16;
  char* bsl = (char*)Bs + tid*16;

  for (int k0 = 0; k0 < K; k0 += 32) {
    __syncthreads();
#ifdef HAVE_GLL
    gll16(A  + (size_t)(bm + lrow)      * lda + k0 + lcol, asl);
    gll16(A  + (size_t)(bm + 64 + lrow) * lda + k0 + lcol, asl + 4096);
    gll16(Bt + (size_t)(bn + lrow)      * K   + k0 + lcol, bsl);
    gll16(Bt + (size_t)(bn + 64 + lrow) * K   + k0 + lcol, bsl + 4096);
#else
    uint4 a0v = *(const uint4*)(const void*)(A  + (size_t)(bm + lrow)      * lda + k0 + lcol);
    uint4 a1v = *(const uint4*)(const void*)(A  + (size_t)(bm + 64 + lrow) * lda + k0 + lcol);
    uint4 b0v = *(const uint4*)(const void*)(Bt + (size_t)(bn + lrow)      * K   + k0 + lcol);
    uint4 b1v = *(const uint4*)(const void*)(Bt + (size_t)(bn + 64 + lrow) * K   + k0 + lcol);
    *(uint4*)(void*)(asl)        = a0v;
    *(uint4*)(void*)(asl + 4096) = a1v;
    *(uint4*)(void*)(bsl)        = b0v;
    *(uint4*)(void*)(bsl + 4096) = b1v;
#endif
    __syncthreads();

    short8 af[4], bfg[4];
#pragma unroll
    for (int mi=0; mi<4; ++mi)
      af[mi] = *(const short8*)(const void*)(As + (wm*64 + mi*16 + m16)*32 + quad*8);
#pragma unroll
    for (int ni=0; ni<4; ++ni)
      bfg[ni] = *(const short8*)(const void*)(Bs + (wn*64 + ni*16 + m16)*32 + quad*8);
#pragma unroll
    for (int mi=0; mi<4; ++mi)
#pragma unroll
      for (int ni=0; ni<4; ++ni)
        acc[mi][ni] = __builtin_amdgcn_mfma_f32_16x16x32_bf16(af[mi], bfg[ni], acc[mi][ni], 0,0,0);
  }

#pragma unroll
  for (int mi=0; mi<4; ++mi) {
    const int row = bm + wm*64 + mi*16 + quad*4;
#pragma unroll
    for (int ni=0; ni<4; ++ni) {
      const int col = bn + wn*64 + ni*16 + m16;
      if (col < N) {
        if (F32OUT) {
          float* cp = (float*)C;
#pragma unroll
          for (int r=0;r<4;++r) cp[(size_t)(row+r)*N + col] = acc[mi][ni][r];
        } else {
          __hip_bfloat16* cp = (__hip_bfloat16*)C;
#pragma unroll
          for (int r=0;r<4;++r) {
            float x = acc[mi][ni][r];
            if (ACT == 1) {
              if (col < 96) x = tanhf(x);
              else if (col >= 256 && col < 512) x = sigm(x);
            }
            cp[(size_t)(row+r)*N + col] = f2bf(x);
          }
        }
      }
    }
  }
}

// ---------------- K10: per-token prep -> packed records + f32 bonus --------------
__global__ __launch_bounds__(256) void prep_kernel(
    const __hip_bfloat16* __restrict__ RKV,   // M x 3072 (r | k | v) bf16
    const __hip_bfloat16* __restrict__ Wpre,  // M x 2048 bf16
    const __hip_bfloat16* __restrict__ Apre,  // M x 2048 bf16
    const __hip_bfloat16* __restrict__ Vsig,  // M x 512 bf16
    const __hip_bfloat16* __restrict__ Ksig,  // M x 512 bf16
    const float* __restrict__ v_first,
    const float* __restrict__ k_first,
    const float* __restrict__ cosp,
    const float* __restrict__ sinp,
    const float* __restrict__ ln_r,
    const float* __restrict__ ln_k,
    const float* __restrict__ r_k,
    const float* __restrict__ w0,
    const float* __restrict__ a0,
    const float* __restrict__ v0,
    const float* __restrict__ k0b,
    const float* __restrict__ R_bias,
    const float* __restrict__ K_bias,
    const float* __restrict__ V_bias,
    char* __restrict__ rec,          // [B*H*TCH] records of RECB bytes
    float* __restrict__ bonus,       // M x 2048 f32 (seg5 staging)
    int t0)
{
  const int b    = blockIdx.x / TCH;
  const int tloc = blockIdx.x % TCH;
  const int t    = t0 + tloc;
  const int m    = b*TT + t;
  const int tid = threadIdx.x;
  const int h  = tid >> 3;
  const int j  = tid & 7;
  const int hk = h >> 2;
  const int nb = j * 8;
  const int hn = h*64 + nb;
  const int kn = hk*64 + nb;

  const size_t rbase = (size_t)m*3072 + h*64 + nb;
  const size_t kbase = (size_t)m*3072 + 2048 + kn;
  const size_t vbase = kbase + 512;

  float r[8], k[8], v[8];
  float ssr = 0.f, ssk = 0.f;
#pragma unroll
  for (int i=0;i<8;++i) {
    r[i] = bf2f(RKV[rbase+i]) + R_bias[hn+i];
    k[i] = bf2f(RKV[kbase+i]) + K_bias[kn+i];
    v[i] = bf2f(RKV[vbase+i]) + V_bias[kn+i];
    ssr += r[i]*r[i];
    ssk += k[i]*k[i];
  }
  ssr = red8(ssr);
  ssk = red8(ssk);
  const float scr = rsqrtf(ssr*(1.0f/64.0f) + 1e-6f);
  const float sck = rsqrtf(ssk*(1.0f/64.0f) + 1e-6f);
#pragma unroll
  for (int i=0;i<8;++i) {
    r[i] = ln_r[nb+i] * r[i] * scr;
    k[i] = ln_k[nb+i] * k[i] * sck;
  }
  const float sgn = (j < 4) ? -1.0f : 1.0f;
  float rr[8], kr[8];
#pragma unroll
  for (int i=0;i<8;++i) {
    const float cs = cosp[(size_t)m*64 + nb + i];
    const float sn = sinp[(size_t)m*64 + nb + i];
    const float pr = __shfl_xor(r[i], 4);
    const float pk = __shfl_xor(k[i], 4);
    rr[i] = r[i]*cs + sgn*pr*sn;
    kr[i] = k[i]*cs + sgn*pk*sn;
  }
  float av[8], ew[8], wv2[8];
  float ssn = 0.f;
#pragma unroll
  for (int i=0;i<8;++i) {
    const float vs = sigm(bf2f(Vsig[(size_t)m*512 + kn + i]) + v0[kn+i]);
    v[i]  = v[i]  + (v_first[(size_t)m*512 + kn + i] - v[i])  * vs;
    const float ks = sigm(bf2f(Ksig[(size_t)m*512 + kn + i]) + k0b[kn+i]);
    kr[i] = kr[i] + (k_first[(size_t)m*512 + kn + i] - kr[i]) * ks;
    ssn += kr[i]*kr[i];
    av[i] = sigm(bf2f(Apre[(size_t)m*2048 + hn + i]) + a0[hn+i]);
    float wraw = bf2f(Wpre[(size_t)m*2048 + hn + i]) + w0[hn+i];
    const float xs = -wraw;                              // stable softplus
    const float sp = fmaxf(xs, 0.f) + log1pf(expf(-fabsf(xs)));
    const float wv = -sp - 0.5f;
    wv2[i] = wv;
    ew[i] = expf(-expf(wv));
  }
  ssn = red8(ssn);
  const float inrm = 1.0f / (sqrtf(ssn) + 1e-12f);
  float kf[8], kkv[8];
  float bsum = 0.f;
#pragma unroll
  for (int i=0;i<8;++i) {
    kkv[i] = kr[i] * inrm;
    kf[i]  = kr[i] * (1.0f - wv2[i] + av[i]);
    bsum  += rr[i] * kf[i] * r_k[hn+i];
  }
  bsum = red8(bsum);

  char* base = rec + ((size_t)(b*HH + h)*TCH + tloc)*RECB;
  const int klb = nb >> 1;           // this thread covers kl entries klb..klb+3
#pragma unroll
  for (int p=0;p<4;++p) {
    const int i0 = 2*p, i1 = i0 + 1;
    uint4 Aw;
    Aw.x = __float_as_uint(ew[i0]);
    Aw.y = __float_as_uint(ew[i1]);
    Aw.z = pkbf(rr[i0], rr[i1]);
    Aw.w = pkbf(kf[i0], kf[i1]);
    *(uint4*)(void*)(base + (size_t)(klb + p)*16) = Aw;
    uint2 Bw;
    Bw.x = pkbf(kkv[i0], kkv[i1]);
    Bw.y = pkbf(-kkv[i0]*av[i0], -kkv[i1]*av[i1]);   // bb' = -kk*a, premultiplied
    *(uint2*)(void*)(base + 512 + (size_t)(klb + p)*8) = Bw;
  }
  short8 vs8;
#pragma unroll
  for (int i=0;i<8;++i) vs8[i] = (short)bfbits(v[i]);
  *(short8*)(void*)(base + 768 + (size_t)nb*2) = vs8;
#pragma unroll
  for (int i=0;i<8;++i)
    bonus[(size_t)m*2048 + hn + i] = bsum * v[i];
}

// ---------------- K11: RWKV7 scan v12 (8 lanes x 8 k-elems, red8) -----------------
// Block = 128 thr (2 waves); wave = 8 v-rows x 8 g-lanes; each lane owns 8 k
// elements of one v-row (S[8] in registers). Grid B*H*4 = 256 blocks (all CUs).
// The per-step k-reduction becomes an IN-REGISTER 8-dot (pipelined FMA) + red8 =
// only 3 row-local DPP hops (quad_perm x2 + row_half_mirror) -- v6/v9/v10/v11 all
// floored at ~110us with >=5 cross-lane hops in the serial chain (~70cy/hop
// dependent latency); this halves the chain hop count with the cheapest forms.
// A/B loads are broadcast across the 8 v-lanes sharing g (L2-resident records).
// Depth-2 register prefetch (X/Y slots).
__global__ __launch_bounds__(128) void scan_kernel(
    const char* __restrict__ rec,
    float* __restrict__ state,          // f32 [B*H,64,64], carried across chunks
    float* __restrict__ o_out,          // M x 2048 f32 (seg0 staging)
    int t0)
{
  const int blk = blockIdx.x;
  const int bh  = blk & 63;            // XCD-local grouping
  const int q   = blk >> 6;            // 0..3
  const int b   = bh >> 5, h = bh & 31;
  const int tid = threadIdx.x;
  const int vl  = q*16 + (tid >> 3);   // v row 0..63
  const int g   = tid & 7;             // k-group: k in [g*8, g*8+8)

  const char* base = rec + (size_t)bh * TCH * RECB;
  float* sp = state + ((size_t)bh*64 + vl)*64 + g*8;
  float S0=sp[0], S1=sp[1], S2=sp[2], S3=sp[3], S4=sp[4], S5=sp[5], S6=sp[6], S7=sp[7];

  const char* pA = base + g*64;        // 4 consecutive uint4 (kl = g*4 .. g*4+3)
  const char* pB = base + 512 + g*32;  // 2 uint4: {kk01,bb01,kk23,bb23},{kk45,bb45,..}
  const char* pv = base + 768 + vl*2;

  // depth-2 slots
  uint4 a0x,a1x,a2x,a3x,b0x,b1x, a0y,a1y,a2y,a3y,b0y,b1y;
  unsigned short vx, vy;
  a0x = *(const uint4*)(const void*)(pA);
  a1x = *(const uint4*)(const void*)(pA+16);
  a2x = *(const uint4*)(const void*)(pA+32);
  a3x = *(const uint4*)(const void*)(pA+48);
  b0x = *(const uint4*)(const void*)(pB);
  b1x = *(const uint4*)(const void*)(pB+16);
  vx  = *(const unsigned short*)(const void*)(pv);
  a0y = *(const uint4*)(const void*)(pA+RECB);
  a1y = *(const uint4*)(const void*)(pA+RECB+16);
  a2y = *(const uint4*)(const void*)(pA+RECB+32);
  a3y = *(const uint4*)(const void*)(pA+RECB+48);
  b0y = *(const uint4*)(const void*)(pB+RECB);
  b1y = *(const uint4*)(const void*)(pB+RECB+16);
  vy  = *(const unsigned short*)(const void*)(pv+RECB);
  pA += 2*RECB; pB += 2*RECB; pv += 2*RECB;

  int oidx = (b*TT + t0)*CC + h*64 + vl - CC;  // deferred store target (row tt-1)
  float opart = 0.f;

#define STEP(A0,A1,A2,A3,B0,B1,VV, PF, PFOFF, ST)                              \
  {                                                                            \
    const float op = red8(opart);                                              \
    /* in-register 8-dot against kk (B.x/.z hold kk pairs) */                  \
    float d0 = S0*ulo(B0.x) + S1*uhi(B0.x);                                    \
    float d1 = S2*ulo(B0.z) + S3*uhi(B0.z);                                    \
    float d2 = S4*ulo(B1.x) + S5*uhi(B1.x);                                    \
    float d3 = S6*ulo(B1.z) + S7*uhi(B1.z);                                    \
    const float sa = red8((d0+d1)+(d2+d3));                                    \
    if (ST && g == 0) o_out[oidx] = op;                                        \
    const float vf = u2f(VV);                                                  \
    S0 = S0*__uint_as_float(A0.x) + sa*ulo(B0.y) + vf*ulo(A0.w);               \
    S1 = S1*__uint_as_float(A0.y) + sa*uhi(B0.y) + vf*uhi(A0.w);               \
    S2 = S2*__uint_as_float(A1.x) + sa*ulo(B0.w) + vf*ulo(A1.w);               \
    S3 = S3*__uint_as_float(A1.y) + sa*uhi(B0.w) + vf*uhi(A1.w);               \
    S4 = S4*__uint_as_float(A2.x) + sa*ulo(B1.y) + vf*ulo(A2.w);               \
    S5 = S5*__uint_as_float(A2.y) + sa*uhi(B1.y) + vf*uhi(A2.w);               \
    S6 = S6*__uint_as_float(A3.x) + sa*ulo(B1.w) + vf*ulo(A3.w);               \
    S7 = S7*__uint_as_float(A3.y) + sa*uhi(B1.w) + vf*uhi(A3.w);               \
    float e0 = S0*ulo(A0.z) + S1*uhi(A0.z);                                    \
    float e1 = S2*ulo(A1.z) + S3*uhi(A1.z);                                    \
    float e2 = S4*ulo(A2.z) + S5*uhi(A2.z);                                    \
    float e3 = S6*ulo(A3.z) + S7*uhi(A3.z);                                    \
    opart = (e0+e1)+(e2+e3);                                                   \
    oidx += CC;                                                                \
    if (PF) {                                                                  \
      A0 = *(const uint4*)(const void*)(pA + (PFOFF));                         \
      A1 = *(const uint4*)(const void*)(pA + (PFOFF) + 16);                    \
      A2 = *(const uint4*)(const void*)(pA + (PFOFF) + 32);                    \
      A3 = *(const uint4*)(const void*)(pA + (PFOFF) + 48);                    \
      B0 = *(const uint4*)(const void*)(pB + (PFOFF));                         \
      B1 = *(const uint4*)(const void*)(pB + (PFOFF) + 16);                    \
      VV = *(const unsigned short*)(const void*)(pv + (PFOFF));                \
    }                                                                          \
  }

  // steps 0 (no store), 1
  STEP(a0x,a1x,a2x,a3x,b0x,b1x,vx, 1, 0,    0)
  STEP(a0y,a1y,a2y,a3y,b0y,b1y,vy, 1, RECB, 1)
  pA += 2*RECB; pB += 2*RECB; pv += 2*RECB;

  for (int t = 2; t < TCH-2; t += 2) {
    STEP(a0x,a1x,a2x,a3x,b0x,b1x,vx, 1, 0,    1)
    STEP(a0y,a1y,a2y,a3y,b0y,b1y,vy, 1, RECB, 1)
    pA += 2*RECB; pB += 2*RECB; pv += 2*RECB;
  }
  STEP(a0x,a1x,a2x,a3x,b0x,b1x,vx, 0, 0, 1)
  STEP(a0y,a1y,a2y,a3y,b0y,b1y,vy, 0, 0, 1)
#undef STEP

  {
    const float op = red8(opart);
    if (g == 0) o_out[oidx] = op;      // row t0+TCH-1
  }

  sp[0]=S0; sp[1]=S1; sp[2]=S2; sp[3]=S3; sp[4]=S4; sp[5]=S5; sp[6]=S6; sp[7]=S7;
}

// ---------------- K12: xxg = (o/8 + bonus) * g -> bf16 ---------------------------
__global__ void xxg_kernel(const float* __restrict__ o_in,
                           const float* __restrict__ bonus,
                           const __hip_bfloat16* __restrict__ G,
                           __hip_bfloat16* __restrict__ xxg)
{
  int i = blockIdx.x*256 + threadIdx.x;
  xxg[i] = f2bf((o_in[i]*0.125f + bonus[i]) * bf2f(G[i]));
}

// ---------------- K14: x_res = x_in + out; output = rmsnorm(x_res, ln2) ----------
__global__ __launch_bounds__(256) void final_kernel(
    const float* __restrict__ x_in,
    const float* __restrict__ OUTb,
    const float* __restrict__ ln2,
    float* __restrict__ seg0,
    float* __restrict__ seg5)
{
  const int m = blockIdx.x;
  const int tid = threadIdx.x;
  const int c = tid*8;
  const float* xp = x_in + (size_t)m*CC + c;
  const float* op = OUTb + (size_t)m*CC + c;
  float xr[8]; float ss = 0.f;
#pragma unroll
  for (int i=0;i<8;++i){ xr[i] = xp[i] + op[i]; ss += xr[i]*xr[i]; }
#pragma unroll
  for (int i=0;i<8;++i) seg5[(size_t)m*CC + c + i] = xr[i];
  ss = red64(ss);
  __shared__ float wsum[4];
  if ((tid&63)==0) wsum[tid>>6] = ss;
  __syncthreads();
  ss = wsum[0]+wsum[1]+wsum[2]+wsum[3];
  const float sc = rsqrtf(ss*(1.0f/CC) + 1e-6f);
#pragma unroll
  for (int i=0;i<8;++i) seg0[(size_t)m*CC + c + i] = ln2[c+i] * xr[i] * sc;
}

extern "C" void kernel_launch(void* const* d_in, const int* in_sizes, int n_in,
                              void* d_out, int out_size, void* d_ws, size_t ws_size,
                              hipStream_t stream)
{
  (void)in_sizes; (void)n_in; (void)out_size; (void)ws_size;
  const float* x_in   = (const float*)d_in[0];
  const float* v_first= (const float*)d_in[1];
  const float* k_first= (const float*)d_in[2];
  const float* state0 = (const float*)d_in[3];
  const float* cosp   = (const float*)d_in[4];
  const float* sinp   = (const float*)d_in[5];
  const float* ln1    = (const float*)d_in[6];
  const float* ln2    = (const float*)d_in[7];
  const float* ln_r   = (const float*)d_in[8];
  const float* ln_k   = (const float*)d_in[9];
  const float* wavgk1 = (const float*)d_in[10];
  const float* w0     = (const float*)d_in[11];
  const float* w2     = (const float*)d_in[12];
  const float* a0     = (const float*)d_in[13];
  const float* a2     = (const float*)d_in[14];
  const float* v0     = (const float*)d_in[15];
  const float* v2     = (const float*)d_in[16];
  const float* k0b    = (const float*)d_in[17];
  const float* k2     = (const float*)d_in[18];
  const float* g2     = (const float*)d_in[19];
  const float* r_k    = (const float*)d_in[20];
  const float* RKV_W  = (const float*)d_in[21];
  const float* O_W    = (const float*)d_in[22];
  const float* R_bias = (const float*)d_in[23];
  const float* K_bias = (const float*)d_in[24];
  const float* V_bias = (const float*)d_in[25];

  // ---- d_out is FLOAT32 ----
  float* out  = (float*)d_out;
  float* seg0 = out;                 // output (B,T,C)
  float* seg1 = out + 4194304;       // x[:, -1] (B,C)
  float* seg2 = out + 4198400;       // state
  float* seg3 = out + 4460544;       // v_first
  float* seg4 = out + 5509120;       // k_first
  float* seg5 = out + 6557696;       // x_res (B,T,C)

  // ---- workspace layout, peak 91,488,256 B (~87.3 MiB) ----
  char* ws = (char*)d_ws;
  const size_t OFF_STF   = 0;                     // f32 state, 1,048,576
  const size_t OFF_OWT   = 1048576;               // O_W^T bf16 2048x2048, 8,388,608
  const size_t OFF_G     = 9437184;               // bf16 M x 2048, 8,388,608
  const size_t OFF_VSIG  = 17825792;              // bf16 M x 512, 2,097,152
  const size_t OFF_KSIG  = 19922944;              // bf16 M x 512
  const size_t OFF_WPRE  = 22020096;              // bf16 M x 2048, 8,388,608
  const size_t OFF_APRE  = 30408704;              // bf16 M x 2048
  const size_t OFF_RKV   = 38797312;              // bf16 M x 3072, 12,582,912
  const size_t OFF_XBF   = 51380224;              // bf16 M x 2048 (dead after x GEMMs)
  const size_t OFF_Y1    = 59768832;              // bf16 M x 576, 2,359,296
  const size_t OFF_WT    = 62128128;              // transposed weights (dead after GEMMs)
  const size_t OFF_WAVT  = OFF_WT;                //  640x2048 bf16, 2,621,440
  const size_t OFF_RKVT  = OFF_WAVT + 2621440;    // 3072x2048 bf16, 12,582,912
  const size_t OFF_W2T   = OFF_RKVT + 12582912;   // 2048x96 bf16, 393,216
  const size_t OFF_A2T   = OFF_W2T  + 393216;
  const size_t OFF_V2T   = OFF_A2T  + 393216;     // 512x64 bf16, 65,536
  const size_t OFF_K2T   = OFF_V2T  + 65536;
  const size_t OFF_G2T   = OFF_K2T  + 65536;      // 2048x256 bf16, 1,048,576
  // overlays:
  const size_t OFF_REC   = OFF_WT;                // records 64*512*896 = 29,360,128 (over WT, dead)
  const size_t OFF_XXG   = OFF_XBF;               // bf16 M x 2048 over x_bf (dead)
  const size_t OFF_OUT   = OFF_WPRE;              // f32 M x 2048 over Wpre+Apre (dead)

  float*          stf   = (float*)(ws + OFF_STF);
  __hip_bfloat16* owt   = (__hip_bfloat16*)(ws + OFF_OWT);
  __hip_bfloat16* Gbuf  = (__hip_bfloat16*)(ws + OFF_G);
  __hip_bfloat16* Vsig  = (__hip_bfloat16*)(ws + OFF_VSIG);
  __hip_bfloat16* Ksig  = (__hip_bfloat16*)(ws + OFF_KSIG);
  __hip_bfloat16* Wpre  = (__hip_bfloat16*)(ws + OFF_WPRE);
  __hip_bfloat16* Apre  = (__hip_bfloat16*)(ws + OFF_APRE);
  __hip_bfloat16* RKV   = (__hip_bfloat16*)(ws + OFF_RKV);
  __hip_bfloat16* x_bf  = (__hip_bfloat16*)(ws + OFF_XBF);
  __hip_bfloat16* Y1    = (__hip_bfloat16*)(ws + OFF_Y1);
  __hip_bfloat16* wavt  = (__hip_bfloat16*)(ws + OFF_WAVT);
  __hip_bfloat16* rkvt  = (__hip_bfloat16*)(ws + OFF_RKVT);
  __hip_bfloat16* w2t   = (__hip_bfloat16*)(ws + OFF_W2T);
  __hip_bfloat16* a2t   = (__hip_bfloat16*)(ws + OFF_A2T);
  __hip_bfloat16* v2t   = (__hip_bfloat16*)(ws + OFF_V2T);
  __hip_bfloat16* k2t   = (__hip_bfloat16*)(ws + OFF_K2T);
  __hip_bfloat16* g2t   = (__hip_bfloat16*)(ws + OFF_G2T);
  char*           rec   = ws + OFF_REC;
  __hip_bfloat16* xxg   = (__hip_bfloat16*)(ws + OFF_XXG);
  float*          OUTb  = (float*)(ws + OFF_OUT);

  float* o_st = seg0;   // o staged in seg0 (rewritten by final)
  float* b_st = seg5;   // bonus staged in seg5 (rewritten by final)

  // weight transposes (f32 -> bf16, [K,N] -> [Npad,K])
  tcvt_kernel<<<dim3(20, 64), 256, 0, stream>>>(wavgk1, wavt, 2048, 576, 640);
  tcvt_kernel<<<dim3(96, 64), 256, 0, stream>>>(RKV_W,  rkvt, 2048, 3072, 3072);
  tcvt_kernel<<<dim3(64, 64), 256, 0, stream>>>(O_W,    owt,  2048, 2048, 2048);
  tcvt_kernel<<<dim3(64,  3), 256, 0, stream>>>(w2,     w2t,    96, 2048, 2048);
  tcvt_kernel<<<dim3(64,  3), 256, 0, stream>>>(a2,     a2t,    96, 2048, 2048);
  tcvt_kernel<<<dim3(16,  2), 256, 0, stream>>>(v2,     v2t,    64,  512,  512);
  tcvt_kernel<<<dim3(16,  2), 256, 0, stream>>>(k2,     k2t,    64,  512,  512);
  tcvt_kernel<<<dim3(64,  8), 256, 0, stream>>>(g2,     g2t,   256, 2048, 2048);

  rmsnorm1_kernel<<<MM, 256, 0, stream>>>(x_in, ln1, x_bf, seg1);
  mgemm<false,1><<<dim3(16,  5), 256, 0, stream>>>(x_bf, CC, wavt, Y1,   576, 2048);
  mgemm<false,0><<<dim3(16, 24), 256, 0, stream>>>(x_bf, CC, rkvt, RKV, 3072, 2048);
  mgemm<false,0><<<dim3(16, 16), 256, 0, stream>>>(Y1+0,   576, w2t, Wpre, 2048, 96);
  mgemm<false,0><<<dim3(16, 16), 256, 0, stream>>>(Y1+96,  576, a2t, Apre, 2048, 96);
  mgemm<false,0><<<dim3(16,  4), 256, 0, stream>>>(Y1+192, 576, v2t, Vsig,  512, 64);
  mgemm<false,0><<<dim3(16,  4), 256, 0, stream>>>(Y1+512, 576, k2t, Ksig,  512, 64);
  mgemm<false,0><<<dim3(16, 16), 256, 0, stream>>>(Y1+256, 576, g2t, Gbuf, 2048, 256);

  hipMemcpyAsync(stf, state0, (size_t)1048576, hipMemcpyDeviceToDevice, stream);
  for (int c = 0; c < NCH; ++c) {
    const int t0 = c*TCH;
    prep_kernel<<<BT*TCH, 256, 0, stream>>>(RKV, Wpre, Apre, Vsig, Ksig, v_first, k_first,
                                            cosp, sinp, ln_r, ln_k, r_k, w0, a0, v0, k0b,
                                            R_bias, K_bias, V_bias, rec, b_st, t0);
    scan_kernel<<<BT*HH*4, 128, 0, stream>>>(rec, stf, o_st, t0);
  }
  hipMemcpyAsync(seg2, stf, (size_t)1048576, hipMemcpyDeviceToDevice, stream);

  xxg_kernel<<<(MM*CC)/256, 256, 0, stream>>>(o_st, b_st, Gbuf, xxg);
  mgemm<true,0><<<dim3(16, 16), 256, 0, stream>>>(xxg, CC, owt, OUTb, 2048, 2048);
  final_kernel<<<MM, 256, 0, stream>>>(x_in, OUTb, ln2, seg0, seg5);

  hipMemcpyAsync(seg3, v_first, (size_t)1048576*4, hipMemcpyDeviceToDevice, stream);
  hipMemcpyAsync(seg4, k_first, (size_t)1048576*4, hipMemcpyDeviceToDevice, stream);
}

// Round 13
// 657.251 us; speedup vs baseline: 1.0959x; 1.0959x over previous
//
#include <hip/hip_runtime.h>
#include <hip/hip_bf16.h>

#define BT 2
#define TT 1024
#define CC 2048
#define HH 32
#define MM (BT*TT)
#define TCH 512          // scan/prep chunk length
#define NCH (TT/TCH)     // 2 chunks
// record layout (896 B): [0,512) per-kl 16B {ew0,ew1,r(bf16x2),kf(bf16x2)}
//                        [512,768) per-kl 8B {kk(bf16x2), -kk*a(bf16x2)}
//                        [768,896) v[64] bf16
#define RECB 896

typedef __attribute__((ext_vector_type(8))) short short8;
typedef __attribute__((ext_vector_type(4))) float floatx4;

static __device__ __forceinline__ float bf2f(__hip_bfloat16 x){ return __bfloat162float(x); }
static __device__ __forceinline__ __hip_bfloat16 f2bf(float x){ return __float2bfloat16(x); }
static __device__ __forceinline__ float sigm(float x){ return 1.0f/(1.0f + expf(-x)); }
static __device__ __forceinline__ float u2f(unsigned short u){
  union { unsigned int i; float f; } x; x.i = ((unsigned int)u) << 16; return x.f;
}
static __device__ __forceinline__ float ulo(unsigned int u){ return __uint_as_float(u << 16); }
static __device__ __forceinline__ float uhi(unsigned int u){ return __uint_as_float(u & 0xffff0000u); }
static __device__ __forceinline__ unsigned short bfbits(float x){
  __hip_bfloat16 h = f2bf(x);
  unsigned short s; __builtin_memcpy(&s, &h, 2); return s;
}
static __device__ __forceinline__ unsigned int pkbf(float lo, float hi){
  return (unsigned int)bfbits(lo) | ((unsigned int)bfbits(hi) << 16);
}

// ---- VALU-only cross-lane reductions (DPP + permlane_swap builtins) ------------
#define DPP_ADD(x, ctrl) ((x) + __int_as_float(__builtin_amdgcn_update_dpp(0, __float_as_int(x), (ctrl), 0xF, 0xF, true)))

#if defined(__has_builtin)
#if __has_builtin(__builtin_amdgcn_permlane16_swap) && __has_builtin(__builtin_amdgcn_permlane32_swap)
#define HAVE_PLSWAP 1
#endif
#endif

#ifdef HAVE_PLSWAP
typedef unsigned int uint2v __attribute__((ext_vector_type(2)));
static __device__ __forceinline__ float row16_pair_add(float x){   // x[i] + x[i^16]
  unsigned int u = __float_as_uint(x);
  uint2v r = __builtin_amdgcn_permlane16_swap(u, u, false, false);
  return __uint_as_float(r[0]) + __uint_as_float(r[1]);
}
static __device__ __forceinline__ float half32_pair_add(float x){  // x[i] + x[i^32]
  unsigned int u = __float_as_uint(x);
  uint2v r = __builtin_amdgcn_permlane32_swap(u, u, false, false);
  return __uint_as_float(r[0]) + __uint_as_float(r[1]);
}
#else
static __device__ __forceinline__ float row16_pair_add(float x){ return x + __shfl_xor(x, 16); }
static __device__ __forceinline__ float half32_pair_add(float x){ return x + __shfl_xor(x, 32); }
#endif

static __device__ __forceinline__ float red8(float x){   // sum over lanes sharing tid>>3
  x = DPP_ADD(x, 0xB1);    // quad_perm xor1
  x = DPP_ADD(x, 0x4E);    // quad_perm xor2
  x = DPP_ADD(x, 0x141);   // row_half_mirror
  return x;
}
static __device__ __forceinline__ float red32(float x){  // sum over 32-lane half-wave
  x = DPP_ADD(x, 0xB1);
  x = DPP_ADD(x, 0x4E);
  x = DPP_ADD(x, 0x124);   // row_ror:4
  x = DPP_ADD(x, 0x128);   // row_ror:8
  return row16_pair_add(x);
}
static __device__ __forceinline__ float red64(float x){  // sum over whole wave
  x = DPP_ADD(x, 0xB1);
  x = DPP_ADD(x, 0x4E);
  x = DPP_ADD(x, 0x124);
  x = DPP_ADD(x, 0x128);
  x = row16_pair_add(x);
  return half32_pair_add(x);
}

// ---------------- K0: transpose + convert weights: Wt[n][k] = bf16(W[k][n]) ------
__global__ __launch_bounds__(256) void tcvt_kernel(
    const float* __restrict__ W, __hip_bfloat16* __restrict__ Wt,
    int K, int N, int Npad)
{
  __shared__ float tile[32][33];
  const int bn = blockIdx.x*32, bk = blockIdx.y*32;
  const int tx = threadIdx.x & 31, ty0 = threadIdx.x >> 5;   // 8 rows/pass
#pragma unroll
  for (int i=0;i<4;++i){
    const int kk = bk + ty0 + i*8;
    float val = 0.f;
    if (kk < K && bn + tx < N) val = W[(size_t)kk*N + bn + tx];
    tile[ty0 + i*8][tx] = val;
  }
  __syncthreads();
#pragma unroll
  for (int i=0;i<4;++i){
    const int nn = bn + ty0 + i*8;
    const int kk = bk + tx;
    if (nn < Npad && kk < K) Wt[(size_t)nn*K + kk] = f2bf(tile[tx][ty0 + i*8]);
  }
}

// ---------------- K1: rmsnorm(x_in, ln1) -> x_bf bf16; x[:, -1] -> seg1 f32 ------
__global__ __launch_bounds__(256) void rmsnorm1_kernel(
    const float* __restrict__ x_in,
    const float* __restrict__ ln1,
    __hip_bfloat16* __restrict__ x_bf,
    float* __restrict__ x_last)
{
  const int m = blockIdx.x;
  const int tid = threadIdx.x;
  const int c = tid * 8;
  const float* xp = x_in + (size_t)m*CC + c;
  float v[8]; float ss = 0.f;
#pragma unroll
  for (int i=0;i<8;++i){ v[i] = xp[i]; ss += v[i]*v[i]; }
  ss = red64(ss);
  __shared__ float wsum[4];
  if ((tid&63)==0) wsum[tid>>6] = ss;
  __syncthreads();
  ss = wsum[0]+wsum[1]+wsum[2]+wsum[3];
  const float sc = rsqrtf(ss * (1.0f/CC) + 1e-6f);
#pragma unroll
  for (int i=0;i<8;++i) {
    const float y = ln1[c+i] * v[i] * sc;
    x_bf[(size_t)m*CC + c + i] = f2bf(y);
    if ((m % TT) == TT-1) x_last[(size_t)(m/TT)*CC + c + i] = y;
  }
}

// ------- MFMA bf16 GEMM: C[M,N] = A_bf16[M,K](lda) @ Wt_bf16[Npad,K]^T -----------
template<bool F32OUT>
__global__ __launch_bounds__(256) void mgemm(
    const __hip_bfloat16* __restrict__ A, int lda,
    const __hip_bfloat16* __restrict__ Bt,
    void* __restrict__ C, int N, int K)
{
  __shared__ __align__(16) short As[128*32];
  __shared__ __align__(16) short Bs[128*32];
  const int tid = threadIdx.x;
  const int bm = blockIdx.x * 128;
  const int bn = blockIdx.y * 128;
  const int wid = tid >> 6;
  const int lane = tid & 63;
  const int m16 = lane & 15, quad = lane >> 4;
  const int wm = wid & 1, wn = wid >> 1;
  const int lrow = tid >> 2;          // 0..63
  const int lcol = (tid & 3) * 8;     // bf16 elems: 0,8,16,24

  floatx4 acc[4][4];
#pragma unroll
  for (int i=0;i<4;++i)
#pragma unroll
    for (int j=0;j<4;++j) acc[i][j] = (floatx4){0.f,0.f,0.f,0.f};

  for (int k0 = 0; k0 < K; k0 += 32) {
    __syncthreads();
    uint4 a0v = *(const uint4*)(const void*)(A  + (size_t)(bm + lrow)      * lda + k0 + lcol);
    uint4 a1v = *(const uint4*)(const void*)(A  + (size_t)(bm + 64 + lrow) * lda + k0 + lcol);
    uint4 b0v = *(const uint4*)(const void*)(Bt + (size_t)(bn + lrow)      * K   + k0 + lcol);
    uint4 b1v = *(const uint4*)(const void*)(Bt + (size_t)(bn + 64 + lrow) * K   + k0 + lcol);
    *(uint4*)(void*)(As + lrow*32 + lcol)        = a0v;
    *(uint4*)(void*)(As + (64 + lrow)*32 + lcol) = a1v;
    *(uint4*)(void*)(Bs + lrow*32 + lcol)        = b0v;
    *(uint4*)(void*)(Bs + (64 + lrow)*32 + lcol) = b1v;
    __syncthreads();

    short8 af[4], bfg[4];
#pragma unroll
    for (int mi=0; mi<4; ++mi)
      af[mi] = *(const short8*)(const void*)(As + (wm*64 + mi*16 + m16)*32 + quad*8);
#pragma unroll
    for (int ni=0; ni<4; ++ni)
      bfg[ni] = *(const short8*)(const void*)(Bs + (wn*64 + ni*16 + m16)*32 + quad*8);
#pragma unroll
    for (int mi=0; mi<4; ++mi)
#pragma unroll
      for (int ni=0; ni<4; ++ni)
        acc[mi][ni] = __builtin_amdgcn_mfma_f32_16x16x32_bf16(af[mi], bfg[ni], acc[mi][ni], 0,0,0);
  }

#pragma unroll
  for (int mi=0; mi<4; ++mi) {
    const int row = bm + wm*64 + mi*16 + quad*4;
#pragma unroll
    for (int ni=0; ni<4; ++ni) {
      const int col = bn + wn*64 + ni*16 + m16;
      if (col < N) {
        if (F32OUT) {
          float* cp = (float*)C;
#pragma unroll
          for (int r=0;r<4;++r) cp[(size_t)(row+r)*N + col] = acc[mi][ni][r];
        } else {
          __hip_bfloat16* cp = (__hip_bfloat16*)C;
#pragma unroll
          for (int r=0;r<4;++r) cp[(size_t)(row+r)*N + col] = f2bf(acc[mi][ni][r]);
        }
      }
    }
  }
}

// ---------------- K4: activations on the 576-wide LoRA inputs, in-place bf16 -----
__global__ void act576_kernel(__hip_bfloat16* __restrict__ Y1)
{
  int i = blockIdx.x*256 + threadIdx.x;
  if (i >= MM*576) return;
  int col = i % 576;
  float v = bf2f(Y1[i]);
  if (col < 96) v = tanhf(v);                       // xw -> tanh
  else if (col >= 256 && col < 512) v = sigm(v);    // xg -> sigmoid
  Y1[i] = f2bf(v);
}

// ---------------- K10: per-token prep -> packed records + f32 bonus --------------
__global__ __launch_bounds__(256) void prep_kernel(
    const __hip_bfloat16* __restrict__ RKV,   // M x 3072 (r | k | v) bf16
    const __hip_bfloat16* __restrict__ Wpre,  // M x 2048 bf16
    const __hip_bfloat16* __restrict__ Apre,  // M x 2048 bf16
    const __hip_bfloat16* __restrict__ Vsig,  // M x 512 bf16
    const __hip_bfloat16* __restrict__ Ksig,  // M x 512 bf16
    const float* __restrict__ v_first,
    const float* __restrict__ k_first,
    const float* __restrict__ cosp,
    const float* __restrict__ sinp,
    const float* __restrict__ ln_r,
    const float* __restrict__ ln_k,
    const float* __restrict__ r_k,
    const float* __restrict__ w0,
    const float* __restrict__ a0,
    const float* __restrict__ v0,
    const float* __restrict__ k0b,
    const float* __restrict__ R_bias,
    const float* __restrict__ K_bias,
    const float* __restrict__ V_bias,
    char* __restrict__ rec,          // [B*H*TCH] records of RECB bytes
    float* __restrict__ bonus,       // M x 2048 f32 (seg5 staging)
    int t0)
{
  const int b    = blockIdx.x / TCH;
  const int tloc = blockIdx.x % TCH;
  const int t    = t0 + tloc;
  const int m    = b*TT + t;
  const int tid = threadIdx.x;
  const int h  = tid >> 3;
  const int j  = tid & 7;
  const int hk = h >> 2;
  const int nb = j * 8;
  const int hn = h*64 + nb;
  const int kn = hk*64 + nb;

  const size_t rbase = (size_t)m*3072 + h*64 + nb;
  const size_t kbase = (size_t)m*3072 + 2048 + kn;
  const size_t vbase = kbase + 512;

  float r[8], k[8], v[8];
  float ssr = 0.f, ssk = 0.f;
#pragma unroll
  for (int i=0;i<8;++i) {
    r[i] = bf2f(RKV[rbase+i]) + R_bias[hn+i];
    k[i] = bf2f(RKV[kbase+i]) + K_bias[kn+i];
    v[i] = bf2f(RKV[vbase+i]) + V_bias[kn+i];
    ssr += r[i]*r[i];
    ssk += k[i]*k[i];
  }
  ssr = red8(ssr);
  ssk = red8(ssk);
  const float scr = rsqrtf(ssr*(1.0f/64.0f) + 1e-6f);
  const float sck = rsqrtf(ssk*(1.0f/64.0f) + 1e-6f);
#pragma unroll
  for (int i=0;i<8;++i) {
    r[i] = ln_r[nb+i] * r[i] * scr;
    k[i] = ln_k[nb+i] * k[i] * sck;
  }
  const float sgn = (j < 4) ? -1.0f : 1.0f;
  float rr[8], kr[8];
#pragma unroll
  for (int i=0;i<8;++i) {
    const float cs = cosp[(size_t)m*64 + nb + i];
    const float sn = sinp[(size_t)m*64 + nb + i];
    const float pr = __shfl_xor(r[i], 4);
    const float pk = __shfl_xor(k[i], 4);
    rr[i] = r[i]*cs + sgn*pr*sn;
    kr[i] = k[i]*cs + sgn*pk*sn;
  }
  float av[8], ew[8], wv2[8];
  float ssn = 0.f;
#pragma unroll
  for (int i=0;i<8;++i) {
    const float vs = sigm(bf2f(Vsig[(size_t)m*512 + kn + i]) + v0[kn+i]);
    v[i]  = v[i]  + (v_first[(size_t)m*512 + kn + i] - v[i])  * vs;
    const float ks = sigm(bf2f(Ksig[(size_t)m*512 + kn + i]) + k0b[kn+i]);
    kr[i] = kr[i] + (k_first[(size_t)m*512 + kn + i] - kr[i]) * ks;
    ssn += kr[i]*kr[i];
    av[i] = sigm(bf2f(Apre[(size_t)m*2048 + hn + i]) + a0[hn+i]);
    float wraw = bf2f(Wpre[(size_t)m*2048 + hn + i]) + w0[hn+i];
    const float xs = -wraw;                              // stable softplus
    const float sp = fmaxf(xs, 0.f) + log1pf(expf(-fabsf(xs)));
    const float wv = -sp - 0.5f;
    wv2[i] = wv;
    ew[i] = expf(-expf(wv));
  }
  ssn = red8(ssn);
  const float inrm = 1.0f / (sqrtf(ssn) + 1e-12f);
  float kf[8], kkv[8];
  float bsum = 0.f;
#pragma unroll
  for (int i=0;i<8;++i) {
    kkv[i] = kr[i] * inrm;
    kf[i]  = kr[i] * (1.0f - wv2[i] + av[i]);
    bsum  += rr[i] * kf[i] * r_k[hn+i];
  }
  bsum = red8(bsum);

  char* base = rec + ((size_t)(b*HH + h)*TCH + tloc)*RECB;
  const int klb = nb >> 1;           // this thread covers kl entries klb..klb+3
#pragma unroll
  for (int p=0;p<4;++p) {
    const int i0 = 2*p, i1 = i0 + 1;
    uint4 Aw;
    Aw.x = __float_as_uint(ew[i0]);
    Aw.y = __float_as_uint(ew[i1]);
    Aw.z = pkbf(rr[i0], rr[i1]);
    Aw.w = pkbf(kf[i0], kf[i1]);
    *(uint4*)(void*)(base + (size_t)(klb + p)*16) = Aw;
    uint2 Bw;
    Bw.x = pkbf(kkv[i0], kkv[i1]);
    Bw.y = pkbf(-kkv[i0]*av[i0], -kkv[i1]*av[i1]);   // bb' = -kk*a, premultiplied
    *(uint2*)(void*)(base + 512 + (size_t)(klb + p)*8) = Bw;
  }
  short8 vs8;
#pragma unroll
  for (int i=0;i<8;++i) vs8[i] = (short)bfbits(v[i]);
  *(short8*)(void*)(base + 768 + (size_t)nb*2) = vs8;
#pragma unroll
  for (int i=0;i<8;++i)
    bonus[(size_t)m*2048 + hn + i] = bsum * v[i];
}

// ---------------- K11: RWKV7 scan v5 ---------------------------------------------
// 256 thr = 8 v-rows x 32 k-lanes (2 k/lane); grid B*H*8; bh in LOW bits -> all
// 8 q-blocks of one bh on the same XCD (records hit L2). Depth-4 named-slot
// prefetch. Clamp-free main loop (t < TCH-4) + 4-step epilogue; region pointers
// advance once per 4 steps with immediate offsets j*896; o-store via running
// 32-bit index; bb' = -kk*a premultiplied in prep.
__global__ __launch_bounds__(256) void scan_kernel(
    const char* __restrict__ rec,
    float* __restrict__ state,          // f32 [B*H,64,64], carried across chunks
    float* __restrict__ o_out,          // M x 2048 f32 (seg0 staging)
    int t0)
{
  const int blk = blockIdx.x;
  const int bh  = blk & 63;            // XCD-local grouping
  const int q   = blk >> 6;
  const int b   = bh >> 5, h = bh & 31;
  const int tid = threadIdx.x;
  const int vl  = q*8 + (tid >> 5);    // v row 0..63
  const int kl  = tid & 31;            // k lane
  const int k2  = kl*2;

  const char* base = rec + (size_t)bh * TCH * RECB;
  float* sp = state + ((size_t)bh*64 + vl)*64 + k2;
  float S0=sp[0], S1=sp[1];

  const char* pA = base + kl*16;
  const char* pB = base + 512 + kl*8;
  const char* pv = base + 768 + vl*2;

  uint4 Ab[4]; uint2 Bb[4]; unsigned short vb[4];
#pragma unroll
  for (int s=0;s<4;++s){
    Ab[s] = *(const uint4*)(const void*)(pA + s*RECB);
    Bb[s] = *(const uint2*)(const void*)(pB + s*RECB);
    vb[s] = *(const unsigned short*)(const void*)(pv + s*RECB);
  }
  pA += 4*RECB; pB += 4*RECB; pv += 4*RECB;

  // oidx = index of the deferred store target (row tt-1); guarded for tt==0.
  int oidx = (b*TT + t0)*CC + h*64 + vl - CC;
  int tt = 0;
  float opart = 0.f;

#define SCAN_STEP(jj, PF)                                                      \
  {                                                                            \
    const uint4 A  = Ab[jj];                                                   \
    const uint2 Bv = Bb[jj];                                                   \
    const float vf = u2f(vb[jj]);                                              \
    if (PF) {                                                                  \
      Ab[jj] = *(const uint4*)(const void*)(pA + jj*RECB);                     \
      Bb[jj] = *(const uint2*)(const void*)(pB + jj*RECB);                     \
      vb[jj] = *(const unsigned short*)(const void*)(pv + jj*RECB);            \
    }                                                                          \
    float op = red32(opart);                                                   \
    const float kk0 = ulo(Bv.x), kk1 = uhi(Bv.x);                              \
    float sa = S0*kk0 + S1*kk1;                                                \
    sa = red32(sa);                                                            \
    if (kl == 0 && tt > 0) o_out[oidx] = op;                                   \
    S0 = S0*__uint_as_float(A.x) + sa*ulo(Bv.y) + vf*ulo(A.w);                 \
    S1 = S1*__uint_as_float(A.y) + sa*uhi(Bv.y) + vf*uhi(A.w);                 \
    opart = S0*ulo(A.z) + S1*uhi(A.z);                                         \
    ++tt; oidx += CC;                                                          \
  }

  for (int t = 0; t < TCH-4; t += 4) {
    SCAN_STEP(0, true)
    SCAN_STEP(1, true)
    SCAN_STEP(2, true)
    SCAN_STEP(3, true)
    pA += 4*RECB; pB += 4*RECB; pv += 4*RECB;
  }
  SCAN_STEP(0, false)
  SCAN_STEP(1, false)
  SCAN_STEP(2, false)
  SCAN_STEP(3, false)
#undef SCAN_STEP

  opart = red32(opart);
  if (kl == 0)
    o_out[oidx] = opart;               // row t0+TCH-1

  sp[0]=S0; sp[1]=S1;
}

// ---------------- K12: xxg = (o/8 + bonus) * g -> bf16 ---------------------------
__global__ void xxg_kernel(const float* __restrict__ o_in,
                           const float* __restrict__ bonus,
                           const __hip_bfloat16* __restrict__ G,
                           __hip_bfloat16* __restrict__ xxg)
{
  int i = blockIdx.x*256 + threadIdx.x;
  xxg[i] = f2bf((o_in[i]*0.125f + bonus[i]) * bf2f(G[i]));
}

// ---------------- K14: x_res = x_in + out; output = rmsnorm(x_res, ln2) ----------
__global__ __launch_bounds__(256) void final_kernel(
    const float* __restrict__ x_in,
    const float* __restrict__ OUTb,
    const float* __restrict__ ln2,
    float* __restrict__ seg0,
    float* __restrict__ seg5)
{
  const int m = blockIdx.x;
  const int tid = threadIdx.x;
  const int c = tid*8;
  const float* xp = x_in + (size_t)m*CC + c;
  const float* op = OUTb + (size_t)m*CC + c;
  float xr[8]; float ss = 0.f;
#pragma unroll
  for (int i=0;i<8;++i){ xr[i] = xp[i] + op[i]; ss += xr[i]*xr[i]; }
#pragma unroll
  for (int i=0;i<8;++i) seg5[(size_t)m*CC + c + i] = xr[i];
  ss = red64(ss);
  __shared__ float wsum[4];
  if ((tid&63)==0) wsum[tid>>6] = ss;
  __syncthreads();
  ss = wsum[0]+wsum[1]+wsum[2]+wsum[3];
  const float sc = rsqrtf(ss*(1.0f/CC) + 1e-6f);
#pragma unroll
  for (int i=0;i<8;++i) seg0[(size_t)m*CC + c + i] = ln2[c+i] * xr[i] * sc;
}

extern "C" void kernel_launch(void* const* d_in, const int* in_sizes, int n_in,
                              void* d_out, int out_size, void* d_ws, size_t ws_size,
                              hipStream_t stream)
{
  (void)in_sizes; (void)n_in; (void)out_size; (void)ws_size;
  const float* x_in   = (const float*)d_in[0];
  const float* v_first= (const float*)d_in[1];
  const float* k_first= (const float*)d_in[2];
  const float* state0 = (const float*)d_in[3];
  const float* cosp   = (const float*)d_in[4];
  const float* sinp   = (const float*)d_in[5];
  const float* ln1    = (const float*)d_in[6];
  const float* ln2    = (const float*)d_in[7];
  const float* ln_r   = (const float*)d_in[8];
  const float* ln_k   = (const float*)d_in[9];
  const float* wavgk1 = (const float*)d_in[10];
  const float* w0     = (const float*)d_in[11];
  const float* w2     = (const float*)d_in[12];
  const float* a0     = (const float*)d_in[13];
  const float* a2     = (const float*)d_in[14];
  const float* v0     = (const float*)d_in[15];
  const float* v2     = (const float*)d_in[16];
  const float* k0b    = (const float*)d_in[17];
  const float* k2     = (const float*)d_in[18];
  const float* g2     = (const float*)d_in[19];
  const float* r_k    = (const float*)d_in[20];
  const float* RKV_W  = (const float*)d_in[21];
  const float* O_W    = (const float*)d_in[22];
  const float* R_bias = (const float*)d_in[23];
  const float* K_bias = (const float*)d_in[24];
  const float* V_bias = (const float*)d_in[25];

  // ---- d_out is FLOAT32 ----
  float* out  = (float*)d_out;
  float* seg0 = out;                 // output (B,T,C)
  float* seg1 = out + 4194304;       // x[:, -1] (B,C)
  float* seg2 = out + 4198400;       // state
  float* seg3 = out + 4460544;       // v_first
  float* seg4 = out + 5509120;       // k_first
  float* seg5 = out + 6557696;       // x_res (B,T,C)

  // ---- workspace layout, peak 91,488,256 B (~87.3 MiB) ----
  char* ws = (char*)d_ws;
  const size_t OFF_STF   = 0;                     // f32 state, 1,048,576
  const size_t OFF_OWT   = 1048576;               // O_W^T bf16 2048x2048, 8,388,608
  const size_t OFF_G     = 9437184;               // bf16 M x 2048, 8,388,608
  const size_t OFF_VSIG  = 17825792;              // bf16 M x 512, 2,097,152
  const size_t OFF_KSIG  = 19922944;              // bf16 M x 512
  const size_t OFF_WPRE  = 22020096;              // bf16 M x 2048, 8,388,608
  const size_t OFF_APRE  = 30408704;              // bf16 M x 2048
  const size_t OFF_RKV   = 38797312;              // bf16 M x 3072, 12,582,912
  const size_t OFF_XBF   = 51380224;              // bf16 M x 2048 (dead after x GEMMs)
  const size_t OFF_Y1    = 59768832;              // bf16 M x 576, 2,359,296 (act in-place)
  const size_t OFF_WT    = 62128128;              // transposed weights (dead after GEMMs)
  const size_t OFF_WAVT  = OFF_WT;                //  640x2048 bf16, 2,621,440
  const size_t OFF_RKVT  = OFF_WAVT + 2621440;    // 3072x2048 bf16, 12,582,912
  const size_t OFF_W2T   = OFF_RKVT + 12582912;   // 2048x96 bf16, 393,216
  const size_t OFF_A2T   = OFF_W2T  + 393216;
  const size_t OFF_V2T   = OFF_A2T  + 393216;     // 512x64 bf16, 65,536
  const size_t OFF_K2T   = OFF_V2T  + 65536;
  const size_t OFF_G2T   = OFF_K2T  + 65536;      // 2048x256 bf16, 1,048,576
  // overlays:
  const size_t OFF_REC   = OFF_WT;                // records 64*512*896 = 29,360,128 (over WT, dead)
  const size_t OFF_XXG   = OFF_XBF;               // bf16 M x 2048 over x_bf (dead)
  const size_t OFF_OUT   = OFF_WPRE;              // f32 M x 2048 over Wpre+Apre (dead)

  float*          stf   = (float*)(ws + OFF_STF);
  __hip_bfloat16* owt   = (__hip_bfloat16*)(ws + OFF_OWT);
  __hip_bfloat16* Gbuf  = (__hip_bfloat16*)(ws + OFF_G);
  __hip_bfloat16* Vsig  = (__hip_bfloat16*)(ws + OFF_VSIG);
  __hip_bfloat16* Ksig  = (__hip_bfloat16*)(ws + OFF_KSIG);
  __hip_bfloat16* Wpre  = (__hip_bfloat16*)(ws + OFF_WPRE);
  __hip_bfloat16* Apre  = (__hip_bfloat16*)(ws + OFF_APRE);
  __hip_bfloat16* RKV   = (__hip_bfloat16*)(ws + OFF_RKV);
  __hip_bfloat16* x_bf  = (__hip_bfloat16*)(ws + OFF_XBF);
  __hip_bfloat16* Y1    = (__hip_bfloat16*)(ws + OFF_Y1);
  __hip_bfloat16* wavt  = (__hip_bfloat16*)(ws + OFF_WAVT);
  __hip_bfloat16* rkvt  = (__hip_bfloat16*)(ws + OFF_RKVT);
  __hip_bfloat16* w2t   = (__hip_bfloat16*)(ws + OFF_W2T);
  __hip_bfloat16* a2t   = (__hip_bfloat16*)(ws + OFF_A2T);
  __hip_bfloat16* v2t   = (__hip_bfloat16*)(ws + OFF_V2T);
  __hip_bfloat16* k2t   = (__hip_bfloat16*)(ws + OFF_K2T);
  __hip_bfloat16* g2t   = (__hip_bfloat16*)(ws + OFF_G2T);
  char*           rec   = ws + OFF_REC;
  __hip_bfloat16* xxg   = (__hip_bfloat16*)(ws + OFF_XXG);
  float*          OUTb  = (float*)(ws + OFF_OUT);

  float* o_st = seg0;   // o staged in seg0 (rewritten by final)
  float* b_st = seg5;   // bonus staged in seg5 (rewritten by final)

  // weight transposes (f32 -> bf16, [K,N] -> [Npad,K])
  tcvt_kernel<<<dim3(20, 64), 256, 0, stream>>>(wavgk1, wavt, 2048, 576, 640);
  tcvt_kernel<<<dim3(96, 64), 256, 0, stream>>>(RKV_W,  rkvt, 2048, 3072, 3072);
  tcvt_kernel<<<dim3(64, 64), 256, 0, stream>>>(O_W,    owt,  2048, 2048, 2048);
  tcvt_kernel<<<dim3(64,  3), 256, 0, stream>>>(w2,     w2t,    96, 2048, 2048);
  tcvt_kernel<<<dim3(64,  3), 256, 0, stream>>>(a2,     a2t,    96, 2048, 2048);
  tcvt_kernel<<<dim3(16,  2), 256, 0, stream>>>(v2,     v2t,    64,  512,  512);
  tcvt_kernel<<<dim3(16,  2), 256, 0, stream>>>(k2,     k2t,    64,  512,  512);
  tcvt_kernel<<<dim3(64,  8), 256, 0, stream>>>(g2,     g2t,   256, 2048, 2048);

  rmsnorm1_kernel<<<MM, 256, 0, stream>>>(x_in, ln1, x_bf, seg1);
  mgemm<false><<<dim3(16,  5), 256, 0, stream>>>(x_bf, CC, wavt, Y1,   576, 2048);
  mgemm<false><<<dim3(16, 24), 256, 0, stream>>>(x_bf, CC, rkvt, RKV, 3072, 2048);
  act576_kernel<<<(MM*576+255)/256, 256, 0, stream>>>(Y1);
  mgemm<false><<<dim3(16, 16), 256, 0, stream>>>(Y1+0,   576, w2t, Wpre, 2048, 96);
  mgemm<false><<<dim3(16, 16), 256, 0, stream>>>(Y1+96,  576, a2t, Apre, 2048, 96);
  mgemm<false><<<dim3(16,  4), 256, 0, stream>>>(Y1+192, 576, v2t, Vsig,  512, 64);
  mgemm<false><<<dim3(16,  4), 256, 0, stream>>>(Y1+512, 576, k2t, Ksig,  512, 64);
  mgemm<false><<<dim3(16, 16), 256, 0, stream>>>(Y1+256, 576, g2t, Gbuf, 2048, 256);

  hipMemcpyAsync(stf, state0, (size_t)1048576, hipMemcpyDeviceToDevice, stream);
  for (int c = 0; c < NCH; ++c) {
    const int t0 = c*TCH;
    prep_kernel<<<BT*TCH, 256, 0, stream>>>(RKV, Wpre, Apre, Vsig, Ksig, v_first, k_first,
                                            cosp, sinp, ln_r, ln_k, r_k, w0, a0, v0, k0b,
                                            R_bias, K_bias, V_bias, rec, b_st, t0);
    scan_kernel<<<BT*HH*8, 256, 0, stream>>>(rec, stf, o_st, t0);
  }
  hipMemcpyAsync(seg2, stf, (size_t)1048576, hipMemcpyDeviceToDevice, stream);

  xxg_kernel<<<(MM*CC)/256, 256, 0, stream>>>(o_st, b_st, Gbuf, xxg);
  mgemm<true><<<dim3(16, 16), 256, 0, stream>>>(xxg, CC, owt, OUTb, 2048, 2048);
  final_kernel<<<MM, 256, 0, stream>>>(x_in, OUTb, ln2, seg0, seg5);

  hipMemcpyAsync(seg3, v_first, (size_t)1048576*4, hipMemcpyDeviceToDevice, stream);
  hipMemcpyAsync(seg4, k_first, (size_t)1048576*4, hipMemcpyDeviceToDevice, stream);
}